// Round 9
// baseline (45.543 us; speedup 1.0000x reference)
//
#include <hip/hip_runtime.h>

#define T_LEN   2097152
#define CHUNK   8
#define BLOCK   256
#define NBLK    (T_LEN / (CHUNK * BLOCK))   // 1024
#define NWAVE   (BLOCK / 64)                // 4
#define FINAL_PER (NBLK / 256)              // 4

#define LOG2E 1.44269504088896340736f
#define LN2   0.69314718055994530942f

#if __has_builtin(__builtin_amdgcn_exp2f)
__device__ __forceinline__ float fexp2(float x) { return __builtin_amdgcn_exp2f(x); }
#else
__device__ __forceinline__ float fexp2(float x) { return exp2f(x); }
#endif
#if __has_builtin(__builtin_amdgcn_logf)
__device__ __forceinline__ float flog2(float x) { return __builtin_amdgcn_logf(x); }
#else
__device__ __forceinline__ float flog2(float x) { return log2f(x); }
#endif

// Exact power-of-two renorm: scale so max entry lands in [1,2). Scale is a pure
// power of 2 -> bit-exact, no rounding.
__device__ __forceinline__ void renorm4(float& a, float& b, float& c, float& d, int& e2) {
    float mx = fmaxf(fmaxf(a, b), fmaxf(c, d));
    int ex = (__float_as_int(mx) >> 23) & 0xff;
    float s = __int_as_float((254 - ex) << 23);          // 2^(127-ex)
    a *= s; b *= s; c *= s; d *= s;
    e2 += ex - 127;
}
__device__ __forceinline__ void renorm1(float& a, int& e2) {
    int ex = (__float_as_int(a) >> 23) & 0xff;
    float s = __int_as_float((254 - ex) << 23);
    a *= s;
    e2 += ex - 127;
}

// Ordered 64-lane butterfly over (2x2 mantissa, exp2 int, gold float).
// Linear matmul = 8 FMA, exponents add, renorm each stage. Zero transcendentals.
__device__ __forceinline__ void wave_reduce_lin(float& Pa, float& Pb, float& Pc, float& Pd,
                                                int& e2, float& g, int lane) {
    #pragma unroll
    for (int m = 1; m < 64; m <<= 1) {
        float Oa = __shfl_xor(Pa, m), Ob = __shfl_xor(Pb, m);
        float Oc = __shfl_xor(Pc, m), Od = __shfl_xor(Pd, m);
        int   Oe = __shfl_xor(e2, m);
        g += __shfl_xor(g, m);
        const bool hi = (lane & m) != 0;                 // my segment comes AFTER partner's
        float Xa = hi?Oa:Pa, Xb = hi?Ob:Pb, Xc = hi?Oc:Pc, Xd = hi?Od:Pd;
        float Ya = hi?Pa:Oa, Yb = hi?Pb:Ob, Yc = hi?Pc:Oc, Yd = hi?Pd:Od;
        Pa = Xa*Ya + Xb*Yc;
        Pb = Xa*Yb + Xb*Yd;
        Pc = Xc*Ya + Xd*Yc;
        Pd = Xc*Yb + Xd*Yd;
        e2 += Oe;
        renorm4(Pa, Pb, Pc, Pd, e2);
    }
}

__global__ __launch_bounds__(BLOCK) void crf_partial(
    const float* __restrict__ em,      // [T,2]
    const int*   __restrict__ label,   // [T]
    const int*   __restrict__ wst,     // [T] in 0..2
    const int*   __restrict__ pst,     // [T] in 0..19
    const float* __restrict__ w2w,     // [2,2,2]
    const float* __restrict__ pos,     // [19,2,2]
    float* __restrict__ outP,          // [NBLK,4] mantissas in [1,2)
    int*   __restrict__ outE,          // [NBLK]   exp2
    float* __restrict__ outG)          // [NBLK]   gold partials (natural log)
{
    __shared__ float4 combExp[60];     // exp(w2w_sub[w] + pos_sub[p]), row-major 2x2
    __shared__ float4 wPs[NWAVE];
    __shared__ int    wEs[NWAVE];
    __shared__ float  wGs[NWAVE];

    const int tid = threadIdx.x;
    if (tid < 60) {
        const int w = tid / 20, p = tid % 20;
        float v0 = 0.f, v1 = 0.f, v2 = 0.f, v3 = 0.f;
        if (w < 2)  { v0 += w2w[w*4+0]; v1 += w2w[w*4+1]; v2 += w2w[w*4+2]; v3 += w2w[w*4+3]; }
        if (p < 19) { v0 += pos[p*4+0]; v1 += pos[p*4+1]; v2 += pos[p*4+2]; v3 += pos[p*4+3]; }
        combExp[tid] = make_float4(fexp2(v0 * LOG2E), fexp2(v1 * LOG2E),
                                   fexp2(v2 * LOG2E), fexp2(v3 * LOG2E));
    }
    __syncthreads();

    const int t0 = (blockIdx.x * BLOCK + tid) * CHUNK;

    // ---- global loads (independent, issued up-front) ----
    const float4* emv = (const float4*)(em + 2 * (size_t)t0);
    float4 E0 = emv[0], E1 = emv[1], E2 = emv[2], E3 = emv[3];
    const int4* lv = (const int4*)(label + t0);
    const int4* wv = (const int4*)(wst   + t0);
    const int4* pv = (const int4*)(pst   + t0);
    int4 L0 = lv[0], L1 = lv[1];
    int4 W0 = wv[0], W1 = wv[1];
    int4 Q0 = pv[0], Q1 = pv[1];
    int prev = (t0 == 0) ? 0 : label[t0 - 1];

    // ---- linear-domain fold. (P,e2) = running product of step matrices
    // M[t][i][j] = exp(c[i][j]) * exp(em[t][j]); init directly from M[t0]. ----
    float Pa, Pb, Pc, Pd;
    int   e2 = 0;
    float gEm  = 0.f;      // gold emission sum (log domain, plain adds)
    float gLin = 1.f;      // gold transition product (linear) with exponent eg
    int   eg   = 0;

    {
        const float e0 = E0.x, e1 = E0.y;
        const float f0 = fexp2(e0 * LOG2E), f1 = fexp2(e1 * LOG2E);
        const float4 X = combExp[W0.x*20 + Q0.x];
        const int l = L0.x;
        gEm += l ? e1 : e0;
        gLin *= prev ? (l ? X.w : X.z) : (l ? X.y : X.x);
        prev = l;
        Pa = X.x * f0;  Pb = X.y * f1;
        Pc = X.z * f0;  Pd = X.w * f1;
    }

#define STEP(e0v, e1v, wI, pI, lI)                                         \
    {                                                                      \
        const float e0 = (e0v), e1 = (e1v);                                \
        const float f0 = fexp2(e0 * LOG2E);                                \
        const float f1 = fexp2(e1 * LOG2E);                                \
        const float4 X = combExp[(wI)*20 + (pI)];                          \
        const int l = (lI);                                                \
        gEm += l ? e1 : e0;                                                \
        gLin *= prev ? (l ? X.w : X.z) : (l ? X.y : X.x);                  \
        prev = l;                                                          \
        float na = (Pa*X.x + Pb*X.z) * f0;                                 \
        float nb = (Pa*X.y + Pb*X.w) * f1;                                 \
        float nc = (Pc*X.x + Pd*X.z) * f0;                                 \
        float nd = (Pc*X.y + Pd*X.w) * f1;                                 \
        Pa = na; Pb = nb; Pc = nc; Pd = nd;                                \
    }

    STEP(E0.z, E0.w, W0.y, Q0.y, L0.y)
    STEP(E1.x, E1.y, W0.z, Q0.z, L0.z)
    STEP(E1.z, E1.w, W0.w, Q0.w, L0.w)
    renorm4(Pa, Pb, Pc, Pd, e2);       // growth <= ~2^84 over 4 steps; renorm
    renorm1(gLin, eg);
    STEP(E2.x, E2.y, W1.x, Q1.x, L1.x)
    STEP(E2.z, E2.w, W1.y, Q1.y, L1.y)
    STEP(E3.x, E3.y, W1.z, Q1.z, L1.z)
    STEP(E3.z, E3.w, W1.w, Q1.w, L1.w)
    renorm4(Pa, Pb, Pc, Pd, e2);
#undef STEP

    // gold partial to one natural-log scalar (the only per-thread log2)
    float g = gEm + ((float)eg + flog2(gLin)) * LN2;

    // ---- ordered reductions (fixed order -> deterministic) ----
    const int lane = tid & 63;
    wave_reduce_lin(Pa, Pb, Pc, Pd, e2, g, lane);

    const int wid = tid >> 6;
    if (lane == 0) { wPs[wid] = make_float4(Pa, Pb, Pc, Pd); wEs[wid] = e2; wGs[wid] = g; }
    __syncthreads();
    if (tid == 0) {
        float4 q = wPs[0];
        float Ra = q.x, Rb = q.y, Rc = q.z, Rd = q.w;
        int   re = wEs[0];
        float rg = wGs[0];
        #pragma unroll
        for (int w = 1; w < NWAVE; ++w) {
            float4 t = wPs[w];
            float Ca = Ra*t.x + Rb*t.z;
            float Cb = Ra*t.y + Rb*t.w;
            float Cc = Rc*t.x + Rd*t.z;
            float Cd = Rc*t.y + Rd*t.w;
            Ra = Ca; Rb = Cb; Rc = Cc; Rd = Cd;
            re += wEs[w];
            renorm4(Ra, Rb, Rc, Rd, re);
            rg += wGs[w];
        }
        ((float4*)outP)[blockIdx.x] = make_float4(Ra, Rb, Rc, Rd);
        outE[blockIdx.x] = re;
        outG[blockIdx.x] = rg;
    }
}

__global__ __launch_bounds__(256) void crf_final(
    const float* __restrict__ inP,     // [NBLK,4] mantissas in [1,2)
    const int*   __restrict__ inE,     // [NBLK]
    const float* __restrict__ inG,     // [NBLK]
    float* __restrict__ out)           // [2] = {gold, total} (natural log)
{
    __shared__ float4 wPs[4];
    __shared__ int    wEs[4];
    __shared__ float  wGs[4];

    const int tid  = threadIdx.x;
    const int base = tid * FINAL_PER;

    float4 q = ((const float4*)inP)[base];
    float Pa = q.x, Pb = q.y, Pc = q.z, Pd = q.w;
    int4  ev = ((const int4*)inE)[tid];
    float4 gv = ((const float4*)inG)[tid];
    int   e2 = ev.x + ev.y + ev.z + ev.w;
    float g  = gv.x + gv.y + gv.z + gv.w;
    #pragma unroll
    for (int k = 1; k < FINAL_PER; ++k) {
        float4 r = ((const float4*)inP)[base + k];
        float Ca = Pa*r.x + Pb*r.z;
        float Cb = Pa*r.y + Pb*r.w;
        float Cc = Pc*r.x + Pd*r.z;
        float Cd = Pc*r.y + Pd*r.w;
        Pa = Ca; Pb = Cb; Pc = Cc; Pd = Cd;
    }
    renorm4(Pa, Pb, Pc, Pd, e2);       // growth <= 2^9 over 3 mms

    const int lane = tid & 63;
    wave_reduce_lin(Pa, Pb, Pc, Pd, e2, g, lane);

    const int wid = tid >> 6;
    if (lane == 0) { wPs[wid] = make_float4(Pa, Pb, Pc, Pd); wEs[wid] = e2; wGs[wid] = g; }
    __syncthreads();
    if (tid == 0) {
        float4 q0 = wPs[0];
        float Ra = q0.x, Rb = q0.y, Rc = q0.z, Rd = q0.w;
        int   re = wEs[0];
        float rg = wGs[0];
        #pragma unroll
        for (int w = 1; w < 4; ++w) {
            float4 t = wPs[w];
            float Ca = Ra*t.x + Rb*t.z;
            float Cb = Ra*t.y + Rb*t.w;
            float Cc = Rc*t.x + Rd*t.z;
            float Cd = Rc*t.y + Rd*t.w;
            Ra = Ca; Rb = Cb; Rc = Cc; Rd = Cd;
            re += wEs[w];
            renorm4(Ra, Rb, Rc, Rd, re);
            rg += wGs[w];
        }
        // alpha0 = 0 -> total = log of sum of all 4 entries of the full product.
        out[0] = rg;
        out[1] = ((float)re + flog2(Ra + Rb + Rc + Rd)) * LN2;
    }
}

extern "C" void kernel_launch(void* const* d_in, const int* in_sizes, int n_in,
                              void* d_out, int out_size, void* d_ws, size_t ws_size,
                              hipStream_t stream) {
    const float* em    = (const float*)d_in[0];
    const int*   label = (const int*)  d_in[1];
    const int*   wst   = (const int*)  d_in[2];
    const int*   pst   = (const int*)  d_in[3];
    const float* w2w   = (const float*)d_in[4];
    const float* pos   = (const float*)d_in[5];
    float* out = (float*)d_out;

    float* outP = (float*)d_ws;              // NBLK*4 floats
    int*   outE = (int*)(outP + NBLK * 4);   // NBLK ints
    float* outG = (float*)(outE + NBLK);     // NBLK floats

    // DIAGNOSTIC ROUND: crf_partial dispatched 4x (idempotent — identical
    // inputs -> identical outputs, so correctness and determinism are
    // unaffected). dur_delta vs the 1x baseline (16.97 us), divided by 3,
    // measures k1's true marginal (cache-warm) runtime — attributing the
    // ~17 us budget between k1 / k2 / fixed dispatch overhead.
    crf_partial<<<NBLK, BLOCK, 0, stream>>>(em, label, wst, pst, w2w, pos,
                                            outP, outE, outG);
    crf_partial<<<NBLK, BLOCK, 0, stream>>>(em, label, wst, pst, w2w, pos,
                                            outP, outE, outG);
    crf_partial<<<NBLK, BLOCK, 0, stream>>>(em, label, wst, pst, w2w, pos,
                                            outP, outE, outG);
    crf_partial<<<NBLK, BLOCK, 0, stream>>>(em, label, wst, pst, w2w, pos,
                                            outP, outE, outG);
    crf_final<<<1, 256, 0, stream>>>(outP, outE, outG, out);
}

// Round 10
// 18.887 us; speedup vs baseline: 2.4113x; 2.4113x over previous
//
#include <hip/hip_runtime.h>

#define T_LEN   2097152
#define CHUNK   4
#define BLOCK   256
#define NBLK    (T_LEN / (CHUNK * BLOCK))   // 2048
#define NWAVE   (BLOCK / 64)                // 4
#define FINAL_PER (NBLK / 256)              // 8

#define LOG2E 1.44269504088896340736f
#define LN2   0.69314718055994530942f

#if __has_builtin(__builtin_amdgcn_exp2f)
__device__ __forceinline__ float fexp2(float x) { return __builtin_amdgcn_exp2f(x); }
#else
__device__ __forceinline__ float fexp2(float x) { return exp2f(x); }
#endif
#if __has_builtin(__builtin_amdgcn_logf)
__device__ __forceinline__ float flog2(float x) { return __builtin_amdgcn_logf(x); }
#else
__device__ __forceinline__ float flog2(float x) { return log2f(x); }
#endif

// Exact power-of-two renorm: scale so max entry lands in [1,2). Scale is a pure
// power of 2 -> bit-exact, no rounding.
__device__ __forceinline__ void renorm4(float& a, float& b, float& c, float& d, int& e2) {
    float mx = fmaxf(fmaxf(a, b), fmaxf(c, d));
    int ex = (__float_as_int(mx) >> 23) & 0xff;
    float s = __int_as_float((254 - ex) << 23);          // 2^(127-ex)
    a *= s; b *= s; c *= s; d *= s;
    e2 += ex - 127;
}

// Ordered 64-lane butterfly over (2x2 mantissa, exp2 int, gold float).
// Linear matmul = 8 FMA, exponents add. Renorm every 2 stages: [1,2)-normalized
// entries grow <= 2^7 between renorms -> no overflow possible.
__device__ __forceinline__ void wave_reduce_lin(float& Pa, float& Pb, float& Pc, float& Pd,
                                                int& e2, float& g, int lane) {
    #pragma unroll
    for (int s = 0; s < 6; ++s) {
        const int m = 1 << s;
        float Oa = __shfl_xor(Pa, m), Ob = __shfl_xor(Pb, m);
        float Oc = __shfl_xor(Pc, m), Od = __shfl_xor(Pd, m);
        int   Oe = __shfl_xor(e2, m);
        g += __shfl_xor(g, m);
        const bool hi = (lane & m) != 0;                 // my segment comes AFTER partner's
        float Xa = hi?Oa:Pa, Xb = hi?Ob:Pb, Xc = hi?Oc:Pc, Xd = hi?Od:Pd;
        float Ya = hi?Pa:Oa, Yb = hi?Pb:Ob, Yc = hi?Pc:Oc, Yd = hi?Pd:Od;
        Pa = Xa*Ya + Xb*Yc;
        Pb = Xa*Yb + Xb*Yd;
        Pc = Xc*Ya + Xd*Yc;
        Pd = Xc*Yb + Xd*Yd;
        e2 += Oe;
        if (s & 1) renorm4(Pa, Pb, Pc, Pd, e2);
    }
}

// __launch_bounds__(256, 8): 8 waves/EU -> caps VGPR at 64 so two 256-thread
// blocks per SIMD-quad can be resident (32 waves/CU). Live set is ~30 regs;
// spill risk low. This is the TLP the R9 probe says k1 is starved of.
__global__ __launch_bounds__(BLOCK, 8) void crf_partial(
    const float* __restrict__ em,      // [T,2]
    const int*   __restrict__ label,   // [T]
    const int*   __restrict__ wst,     // [T] in 0..2
    const int*   __restrict__ pst,     // [T] in 0..19
    const float* __restrict__ w2w,     // [2,2,2]
    const float* __restrict__ pos,     // [19,2,2]
    float* __restrict__ outP,          // [NBLK,4] mantissas in [1,2)
    int*   __restrict__ outE,          // [NBLK]   exp2
    float* __restrict__ outG)          // [NBLK]   gold partials (natural log)
{
    __shared__ float4 combExp[60];     // exp(w2w_sub[w] + pos_sub[p]), row-major 2x2
    __shared__ float4 wPs[NWAVE];
    __shared__ int    wEs[NWAVE];
    __shared__ float  wGs[NWAVE];

    const int tid  = threadIdx.x;
    const int wid  = tid >> 6;
    const int lane = tid & 63;

    if (tid < 60) {
        const int w = tid / 20, p = tid % 20;
        float v0 = 0.f, v1 = 0.f, v2 = 0.f, v3 = 0.f;
        if (w < 2)  { v0 += w2w[w*4+0]; v1 += w2w[w*4+1]; v2 += w2w[w*4+2]; v3 += w2w[w*4+3]; }
        if (p < 19) { v0 += pos[p*4+0]; v1 += pos[p*4+1]; v2 += pos[p*4+2]; v3 += pos[p*4+3]; }
        combExp[tid] = make_float4(fexp2(v0 * LOG2E), fexp2(v1 * LOG2E),
                                   fexp2(v2 * LOG2E), fexp2(v3 * LOG2E));
    }
    __syncthreads();

    const size_t t0 = ((size_t)blockIdx.x * BLOCK + tid) * CHUNK;

    // ---- 5 independent 16B loads per thread ----
    const float4* emv = (const float4*)(em + 2 * t0);
    float4 E0 = emv[0], E1 = emv[1];
    int4 L = ((const int4*)(label + t0))[0];
    int4 W = ((const int4*)(wst   + t0))[0];
    int4 Q = ((const int4*)(pst   + t0))[0];

    // prev label: lane i-1's last label == my t0-1. Only lane 0 touches global.
    int prev = __shfl_up(L.w, 1);
    if (lane == 0) prev = (t0 == 0) ? 0 : label[t0 - 1];

    // ---- linear-domain 4-step fold.  M[t][i][j] = exp(c[i][j]) * exp(em[t][j]).
    // 4 renorm-free steps grow <= ~2^94 < 2^127 -> single renorm at the end. ----
    float Pa, Pb, Pc, Pd;
    int   e2 = 0;
    float gEm  = 0.f;      // gold emission sum (natural log, plain adds)
    float gLin = 1.f;      // gold transition product (linear); <= 2^~46, no renorm

    {
        const float f0 = fexp2(E0.x * LOG2E), f1 = fexp2(E0.y * LOG2E);
        const float4 X = combExp[W.x*20 + Q.x];
        const int l = L.x;
        gEm += l ? E0.y : E0.x;
        gLin *= prev ? (l ? X.w : X.z) : (l ? X.y : X.x);
        prev = l;
        Pa = X.x * f0;  Pb = X.y * f1;
        Pc = X.z * f0;  Pd = X.w * f1;
    }

#define STEP(e0v, e1v, wI, pI, lI)                                         \
    {                                                                      \
        const float e0 = (e0v), e1 = (e1v);                                \
        const float f0 = fexp2(e0 * LOG2E);                                \
        const float f1 = fexp2(e1 * LOG2E);                                \
        const float4 X = combExp[(wI)*20 + (pI)];                          \
        const int l = (lI);                                                \
        gEm += l ? e1 : e0;                                                \
        gLin *= prev ? (l ? X.w : X.z) : (l ? X.y : X.x);                  \
        prev = l;                                                          \
        float na = (Pa*X.x + Pb*X.z) * f0;                                 \
        float nb = (Pa*X.y + Pb*X.w) * f1;                                 \
        float nc = (Pc*X.x + Pd*X.z) * f0;                                 \
        float nd = (Pc*X.y + Pd*X.w) * f1;                                 \
        Pa = na; Pb = nb; Pc = nc; Pd = nd;                                \
    }

    STEP(E0.z, E0.w, W.y, Q.y, L.y)
    STEP(E1.x, E1.y, W.z, Q.z, L.z)
    STEP(E1.z, E1.w, W.w, Q.w, L.w)
#undef STEP
    renorm4(Pa, Pb, Pc, Pd, e2);

    // gold partial to one natural-log scalar (the only per-thread log2)
    float g = gEm + flog2(gLin) * LN2;

    // ---- ordered reductions (fixed order -> deterministic) ----
    wave_reduce_lin(Pa, Pb, Pc, Pd, e2, g, lane);

    if (lane == 0) { wPs[wid] = make_float4(Pa, Pb, Pc, Pd); wEs[wid] = e2; wGs[wid] = g; }
    __syncthreads();
    if (tid == 0) {
        float4 q = wPs[0];
        float Ra = q.x, Rb = q.y, Rc = q.z, Rd = q.w;
        int   re = wEs[0];
        float rg = wGs[0];
        #pragma unroll
        for (int w = 1; w < NWAVE; ++w) {
            float4 t = wPs[w];
            float Ca = Ra*t.x + Rb*t.z;
            float Cb = Ra*t.y + Rb*t.w;
            float Cc = Rc*t.x + Rd*t.z;
            float Cd = Rc*t.y + Rd*t.w;
            Ra = Ca; Rb = Cb; Rc = Cc; Rd = Cd;
            re += wEs[w];
            renorm4(Ra, Rb, Rc, Rd, re);
            rg += wGs[w];
        }
        ((float4*)outP)[blockIdx.x] = make_float4(Ra, Rb, Rc, Rd);
        outE[blockIdx.x] = re;
        outG[blockIdx.x] = rg;
    }
}

__global__ __launch_bounds__(256) void crf_final(
    const float* __restrict__ inP,     // [NBLK,4] mantissas in [1,2)
    const int*   __restrict__ inE,     // [NBLK]
    const float* __restrict__ inG,     // [NBLK]
    float* __restrict__ out)           // [2] = {gold, total} (natural log)
{
    __shared__ float4 wPs[4];
    __shared__ int    wEs[4];
    __shared__ float  wGs[4];

    const int tid  = threadIdx.x;
    const int base = tid * FINAL_PER;

    float4 q = ((const float4*)inP)[base];
    float Pa = q.x, Pb = q.y, Pc = q.z, Pd = q.w;
    int4  ev0 = ((const int4*)inE)[2*tid],   ev1 = ((const int4*)inE)[2*tid+1];
    float4 gv0 = ((const float4*)inG)[2*tid], gv1 = ((const float4*)inG)[2*tid+1];
    int   e2 = ev0.x + ev0.y + ev0.z + ev0.w + ev1.x + ev1.y + ev1.z + ev1.w;
    float g  = gv0.x + gv0.y + gv0.z + gv0.w + gv1.x + gv1.y + gv1.z + gv1.w;
    #pragma unroll
    for (int k = 1; k < FINAL_PER; ++k) {
        float4 r = ((const float4*)inP)[base + k];
        float Ca = Pa*r.x + Pb*r.z;
        float Cb = Pa*r.y + Pb*r.w;
        float Cc = Pc*r.x + Pd*r.z;
        float Cd = Pc*r.y + Pd*r.w;
        Pa = Ca; Pb = Cb; Pc = Cc; Pd = Cd;
    }
    // 7 mms of [1,2)-normalized operands grow <= ~2^15 -> one renorm suffices.
    renorm4(Pa, Pb, Pc, Pd, e2);

    const int lane = tid & 63;
    wave_reduce_lin(Pa, Pb, Pc, Pd, e2, g, lane);

    const int wid = tid >> 6;
    if (lane == 0) { wPs[wid] = make_float4(Pa, Pb, Pc, Pd); wEs[wid] = e2; wGs[wid] = g; }
    __syncthreads();
    if (tid == 0) {
        float4 q0 = wPs[0];
        float Ra = q0.x, Rb = q0.y, Rc = q0.z, Rd = q0.w;
        int   re = wEs[0];
        float rg = wGs[0];
        #pragma unroll
        for (int w = 1; w < 4; ++w) {
            float4 t = wPs[w];
            float Ca = Ra*t.x + Rb*t.z;
            float Cb = Ra*t.y + Rb*t.w;
            float Cc = Rc*t.x + Rd*t.z;
            float Cd = Rc*t.y + Rd*t.w;
            Ra = Ca; Rb = Cb; Rc = Cc; Rd = Cd;
            re += wEs[w];
            renorm4(Ra, Rb, Rc, Rd, re);
            rg += wGs[w];
        }
        // alpha0 = 0 -> total = log of sum of all 4 entries of the full product.
        out[0] = rg;
        out[1] = ((float)re + flog2(Ra + Rb + Rc + Rd)) * LN2;
    }
}

extern "C" void kernel_launch(void* const* d_in, const int* in_sizes, int n_in,
                              void* d_out, int out_size, void* d_ws, size_t ws_size,
                              hipStream_t stream) {
    const float* em    = (const float*)d_in[0];
    const int*   label = (const int*)  d_in[1];
    const int*   wst   = (const int*)  d_in[2];
    const int*   pst   = (const int*)  d_in[3];
    const float* w2w   = (const float*)d_in[4];
    const float* pos   = (const float*)d_in[5];
    float* out = (float*)d_out;

    float* outP = (float*)d_ws;              // NBLK*4 floats
    int*   outE = (int*)(outP + NBLK * 4);   // NBLK ints
    float* outG = (float*)(outE + NBLK);     // NBLK floats

    crf_partial<<<NBLK, BLOCK, 0, stream>>>(em, label, wst, pst, w2w, pos,
                                            outP, outE, outG);
    crf_final<<<1, 256, 0, stream>>>(outP, outE, outG, out);
}

// Round 11
// 16.554 us; speedup vs baseline: 2.7512x; 1.1409x over previous
//
#include <hip/hip_runtime.h>

#define T_LEN   2097152
#define CHUNK   8
#define BLOCK   256
#define NBLK    (T_LEN / (CHUNK * BLOCK))   // 1024
#define NWAVE   (BLOCK / 64)                // 4
#define FINAL_PER (NBLK / 256)              // 4

#define LOG2E 1.44269504088896340736f
#define LN2   0.69314718055994530942f

#if __has_builtin(__builtin_amdgcn_exp2f)
__device__ __forceinline__ float fexp2(float x) { return __builtin_amdgcn_exp2f(x); }
#else
__device__ __forceinline__ float fexp2(float x) { return exp2f(x); }
#endif
#if __has_builtin(__builtin_amdgcn_logf)
__device__ __forceinline__ float flog2(float x) { return __builtin_amdgcn_logf(x); }
#else
__device__ __forceinline__ float flog2(float x) { return log2f(x); }
#endif

// ---- DPP cross-lane exchange (VALU pipe) for xor masks 1, 2, 8 ----
// quad_perm [1,0,3,2] = 0xB1 -> lane^1 ; quad_perm [2,3,0,1] = 0x4E -> lane^2 ;
// row_ror:8 (0x128) within 16-lane rows -> lane^8.  Masks 4/16/32 are not
// DPP-expressible on CDNA -> keep __shfl_xor (ds_swizzle/permute, LDS unit).
#if __has_builtin(__builtin_amdgcn_mov_dpp)
#define DPPF(x, C) __int_as_float(__builtin_amdgcn_mov_dpp(__float_as_int(x), (C), 0xF, 0xF, true))
#define DPPI(x, C) __builtin_amdgcn_mov_dpp((x), (C), 0xF, 0xF, true)
#else
// Fallback: plain shuffles (M = xor mask matching the DPP pattern)
#define DPPF(x, C) __shfl_xor((x), ((C) == 0xB1 ? 1 : (C) == 0x4E ? 2 : 8))
#define DPPI(x, C) __shfl_xor((x), ((C) == 0xB1 ? 1 : (C) == 0x4E ? 2 : 8))
#endif

// Exact power-of-two renorm: scale so max entry lands in [1,2). Scale is a pure
// power of 2 -> bit-exact, no rounding.
__device__ __forceinline__ void renorm4(float& a, float& b, float& c, float& d, int& e2) {
    float mx = fmaxf(fmaxf(a, b), fmaxf(c, d));
    int ex = (__float_as_int(mx) >> 23) & 0xff;
    float s = __int_as_float((254 - ex) << 23);          // 2^(127-ex)
    a *= s; b *= s; c *= s; d *= s;
    e2 += ex - 127;
}
__device__ __forceinline__ void renorm1(float& a, int& e2) {
    int ex = (__float_as_int(a) >> 23) & 0xff;
    float s = __int_as_float((254 - ex) << 23);
    a *= s;
    e2 += ex - 127;
}

// Ordered 64-lane butterfly over (2x2 mantissa, exp2 int, gold float).
// Stages m=1,2,8 exchange via DPP (VALU); m=4,16,32 via shfl (LDS unit).
// Renorm every 2 stages: [1,2)-normalized entries grow <= 2^7 between renorms.
// Bit-identical to the all-shfl version (same pairing, same order).
#define BSTAGE(GF, GI, mval, rn)                                              \
    {                                                                         \
        float Oa = GF(Pa), Ob = GF(Pb), Oc = GF(Pc), Od = GF(Pd);             \
        int   Oe = GI(e2);                                                    \
        g += GF(g);                                                           \
        const bool hi = (lane & (mval)) != 0;                                 \
        float Xa = hi?Oa:Pa, Xb = hi?Ob:Pb, Xc = hi?Oc:Pc, Xd = hi?Od:Pd;     \
        float Ya = hi?Pa:Oa, Yb = hi?Pb:Ob, Yc = hi?Pc:Oc, Yd = hi?Pd:Od;     \
        Pa = Xa*Ya + Xb*Yc;                                                   \
        Pb = Xa*Yb + Xb*Yd;                                                   \
        Pc = Xc*Ya + Xd*Yc;                                                   \
        Pd = Xc*Yb + Xd*Yd;                                                   \
        e2 += Oe;                                                             \
        if (rn) renorm4(Pa, Pb, Pc, Pd, e2);                                  \
    }

#define GF1(x)  DPPF(x, 0xB1)
#define GI1(x)  DPPI(x, 0xB1)
#define GF2(x)  DPPF(x, 0x4E)
#define GI2(x)  DPPI(x, 0x4E)
#define GF8(x)  DPPF(x, 0x128)
#define GI8(x)  DPPI(x, 0x128)
#define GF4(x)  __shfl_xor((x), 4)
#define GF16(x) __shfl_xor((x), 16)
#define GF32(x) __shfl_xor((x), 32)

__device__ __forceinline__ void wave_reduce_lin(float& Pa, float& Pb, float& Pc, float& Pd,
                                                int& e2, float& g, int lane) {
    BSTAGE(GF1,  GI1,   1, false)
    BSTAGE(GF2,  GI2,   2, true)
    BSTAGE(GF4,  GF4,   4, false)
    BSTAGE(GF8,  GI8,   8, true)
    BSTAGE(GF16, GF16, 16, false)
    BSTAGE(GF32, GF32, 32, true)
}

__global__ __launch_bounds__(BLOCK) void crf_partial(
    const float* __restrict__ em,      // [T,2]
    const int*   __restrict__ label,   // [T]
    const int*   __restrict__ wst,     // [T] in 0..2
    const int*   __restrict__ pst,     // [T] in 0..19
    const float* __restrict__ w2w,     // [2,2,2]
    const float* __restrict__ pos,     // [19,2,2]
    float* __restrict__ outP,          // [NBLK,4] mantissas in [1,2)
    int*   __restrict__ outE,          // [NBLK]   exp2
    float* __restrict__ outG)          // [NBLK]   gold partials (natural log)
{
    __shared__ float4 combExp[60];     // exp(w2w_sub[w] + pos_sub[p]), row-major 2x2
    __shared__ float4 wPs[NWAVE];
    __shared__ int    wEs[NWAVE];
    __shared__ float  wGs[NWAVE];

    const int tid = threadIdx.x;
    if (tid < 60) {
        const int w = tid / 20, p = tid % 20;
        float v0 = 0.f, v1 = 0.f, v2 = 0.f, v3 = 0.f;
        if (w < 2)  { v0 += w2w[w*4+0]; v1 += w2w[w*4+1]; v2 += w2w[w*4+2]; v3 += w2w[w*4+3]; }
        if (p < 19) { v0 += pos[p*4+0]; v1 += pos[p*4+1]; v2 += pos[p*4+2]; v3 += pos[p*4+3]; }
        combExp[tid] = make_float4(fexp2(v0 * LOG2E), fexp2(v1 * LOG2E),
                                   fexp2(v2 * LOG2E), fexp2(v3 * LOG2E));
    }
    __syncthreads();

    const int t0 = (blockIdx.x * BLOCK + tid) * CHUNK;

    // ---- global loads (independent, issued up-front) ----
    const float4* emv = (const float4*)(em + 2 * (size_t)t0);
    float4 E0 = emv[0], E1 = emv[1], E2 = emv[2], E3 = emv[3];
    const int4* lv = (const int4*)(label + t0);
    const int4* wv = (const int4*)(wst   + t0);
    const int4* pv = (const int4*)(pst   + t0);
    int4 L0 = lv[0], L1 = lv[1];
    int4 W0 = wv[0], W1 = wv[1];
    int4 Q0 = pv[0], Q1 = pv[1];
    int prev = (t0 == 0) ? 0 : label[t0 - 1];

    // ---- linear-domain fold. (P,e2) = running product of step matrices
    // M[t][i][j] = exp(c[i][j]) * exp(em[t][j]); init directly from M[t0]. ----
    float Pa, Pb, Pc, Pd;
    int   e2 = 0;
    float gEm  = 0.f;      // gold emission sum (log domain, plain adds)
    float gLin = 1.f;      // gold transition product (linear) with exponent eg
    int   eg   = 0;

    {
        const float e0 = E0.x, e1 = E0.y;
        const float f0 = fexp2(e0 * LOG2E), f1 = fexp2(e1 * LOG2E);
        const float4 X = combExp[W0.x*20 + Q0.x];
        const int l = L0.x;
        gEm += l ? e1 : e0;
        gLin *= prev ? (l ? X.w : X.z) : (l ? X.y : X.x);
        prev = l;
        Pa = X.x * f0;  Pb = X.y * f1;
        Pc = X.z * f0;  Pd = X.w * f1;
    }

#define STEP(e0v, e1v, wI, pI, lI)                                         \
    {                                                                      \
        const float e0 = (e0v), e1 = (e1v);                                \
        const float f0 = fexp2(e0 * LOG2E);                                \
        const float f1 = fexp2(e1 * LOG2E);                                \
        const float4 X = combExp[(wI)*20 + (pI)];                          \
        const int l = (lI);                                                \
        gEm += l ? e1 : e0;                                                \
        gLin *= prev ? (l ? X.w : X.z) : (l ? X.y : X.x);                  \
        prev = l;                                                          \
        float na = (Pa*X.x + Pb*X.z) * f0;                                 \
        float nb = (Pa*X.y + Pb*X.w) * f1;                                 \
        float nc = (Pc*X.x + Pd*X.z) * f0;                                 \
        float nd = (Pc*X.y + Pd*X.w) * f1;                                 \
        Pa = na; Pb = nb; Pc = nc; Pd = nd;                                \
    }

    STEP(E0.z, E0.w, W0.y, Q0.y, L0.y)
    STEP(E1.x, E1.y, W0.z, Q0.z, L0.z)
    STEP(E1.z, E1.w, W0.w, Q0.w, L0.w)
    renorm4(Pa, Pb, Pc, Pd, e2);       // growth <= ~2^94 over 4 steps; renorm
    renorm1(gLin, eg);
    STEP(E2.x, E2.y, W1.x, Q1.x, L1.x)
    STEP(E2.z, E2.w, W1.y, Q1.y, L1.y)
    STEP(E3.x, E3.y, W1.z, Q1.z, L1.z)
    STEP(E3.z, E3.w, W1.w, Q1.w, L1.w)
    renorm4(Pa, Pb, Pc, Pd, e2);
#undef STEP

    // gold partial to one natural-log scalar (the only per-thread log2)
    float g = gEm + ((float)eg + flog2(gLin)) * LN2;

    // ---- ordered reductions (fixed order -> deterministic) ----
    const int lane = tid & 63;
    wave_reduce_lin(Pa, Pb, Pc, Pd, e2, g, lane);

    const int wid = tid >> 6;
    if (lane == 0) { wPs[wid] = make_float4(Pa, Pb, Pc, Pd); wEs[wid] = e2; wGs[wid] = g; }
    __syncthreads();
    if (tid == 0) {
        float4 q = wPs[0];
        float Ra = q.x, Rb = q.y, Rc = q.z, Rd = q.w;
        int   re = wEs[0];
        float rg = wGs[0];
        #pragma unroll
        for (int w = 1; w < NWAVE; ++w) {
            float4 t = wPs[w];
            float Ca = Ra*t.x + Rb*t.z;
            float Cb = Ra*t.y + Rb*t.w;
            float Cc = Rc*t.x + Rd*t.z;
            float Cd = Rc*t.y + Rd*t.w;
            Ra = Ca; Rb = Cb; Rc = Cc; Rd = Cd;
            re += wEs[w];
            renorm4(Ra, Rb, Rc, Rd, re);
            rg += wGs[w];
        }
        ((float4*)outP)[blockIdx.x] = make_float4(Ra, Rb, Rc, Rd);
        outE[blockIdx.x] = re;
        outG[blockIdx.x] = rg;
    }
}

__global__ __launch_bounds__(256) void crf_final(
    const float* __restrict__ inP,     // [NBLK,4] mantissas in [1,2)
    const int*   __restrict__ inE,     // [NBLK]
    const float* __restrict__ inG,     // [NBLK]
    float* __restrict__ out)           // [2] = {gold, total} (natural log)
{
    __shared__ float4 wPs[4];
    __shared__ int    wEs[4];
    __shared__ float  wGs[4];

    const int tid  = threadIdx.x;
    const int base = tid * FINAL_PER;

    float4 q = ((const float4*)inP)[base];
    float Pa = q.x, Pb = q.y, Pc = q.z, Pd = q.w;
    int4  ev = ((const int4*)inE)[tid];
    float4 gv = ((const float4*)inG)[tid];
    int   e2 = ev.x + ev.y + ev.z + ev.w;
    float g  = gv.x + gv.y + gv.z + gv.w;
    #pragma unroll
    for (int k = 1; k < FINAL_PER; ++k) {
        float4 r = ((const float4*)inP)[base + k];
        float Ca = Pa*r.x + Pb*r.z;
        float Cb = Pa*r.y + Pb*r.w;
        float Cc = Pc*r.x + Pd*r.z;
        float Cd = Pc*r.y + Pd*r.w;
        Pa = Ca; Pb = Cb; Pc = Cc; Pd = Cd;
    }
    renorm4(Pa, Pb, Pc, Pd, e2);       // growth <= 2^9 over 3 mms

    const int lane = tid & 63;
    wave_reduce_lin(Pa, Pb, Pc, Pd, e2, g, lane);

    const int wid = tid >> 6;
    if (lane == 0) { wPs[wid] = make_float4(Pa, Pb, Pc, Pd); wEs[wid] = e2; wGs[wid] = g; }
    __syncthreads();
    if (tid == 0) {
        float4 q0 = wPs[0];
        float Ra = q0.x, Rb = q0.y, Rc = q0.z, Rd = q0.w;
        int   re = wEs[0];
        float rg = wGs[0];
        #pragma unroll
        for (int w = 1; w < 4; ++w) {
            float4 t = wPs[w];
            float Ca = Ra*t.x + Rb*t.z;
            float Cb = Ra*t.y + Rb*t.w;
            float Cc = Rc*t.x + Rd*t.z;
            float Cd = Rc*t.y + Rd*t.w;
            Ra = Ca; Rb = Cb; Rc = Cc; Rd = Cd;
            re += wEs[w];
            renorm4(Ra, Rb, Rc, Rd, re);
            rg += wGs[w];
        }
        // alpha0 = 0 -> total = log of sum of all 4 entries of the full product.
        out[0] = rg;
        out[1] = ((float)re + flog2(Ra + Rb + Rc + Rd)) * LN2;
    }
}

extern "C" void kernel_launch(void* const* d_in, const int* in_sizes, int n_in,
                              void* d_out, int out_size, void* d_ws, size_t ws_size,
                              hipStream_t stream) {
    const float* em    = (const float*)d_in[0];
    const int*   label = (const int*)  d_in[1];
    const int*   wst   = (const int*)  d_in[2];
    const int*   pst   = (const int*)  d_in[3];
    const float* w2w   = (const float*)d_in[4];
    const float* pos   = (const float*)d_in[5];
    float* out = (float*)d_out;

    float* outP = (float*)d_ws;              // NBLK*4 floats
    int*   outE = (int*)(outP + NBLK * 4);   // NBLK ints
    float* outG = (float*)(outE + NBLK);     // NBLK floats

    crf_partial<<<NBLK, BLOCK, 0, stream>>>(em, label, wst, pst, w2w, pos,
                                            outP, outE, outG);
    crf_final<<<1, 256, 0, stream>>>(outP, outE, outG, out);
}